// Round 4
// baseline (243.894 us; speedup 1.0000x reference)
//
#include <hip/hip_runtime.h>

#define S_LEN 2048
#define BATCH 8
#define DIM   64
#define QT    32
#define KT    64
#define NT    (S_LEN / KT)   // 32 k-tiles
#define QP    72             // bf16 LDS pitch (elements)
#define PP    68             // fp32 LDS pitch (elements)
#define EPSV  1e-8f

typedef __attribute__((ext_vector_type(8))) short short8;
typedef __attribute__((ext_vector_type(4))) short short4v;
typedef __attribute__((ext_vector_type(4))) float f32x4;

// round-to-nearest-even fp32 -> bf16 bits
__device__ __forceinline__ short bf16b(float x) {
    unsigned int u = __builtin_bit_cast(unsigned int, x);
    u = (u + 0x7fffu + ((u >> 16) & 1u)) >> 16;
    return (short)u;
}

__global__ __launch_bounds__(256, 4)
void qattn(const float* __restrict__ Qg, const float* __restrict__ Kg,
           const float* __restrict__ Vg, float* __restrict__ out)
{
    __shared__ short Qsh[QT * QP];    // normalized Q, bf16
    __shared__ short Ksh[KT * QP];    // normalized K tile, bf16
    __shared__ short VTs[DIM * QP];   // V tile transposed [d][k], bf16
    __shared__ short Pb [QT * QP];    // probs bf16 (PV A-operand)
    __shared__ float Pf [QT * PP];    // probs fp32 (coalesced global write)
    __shared__ float rsum[QT];

    const int tid = threadIdx.x;
    const int l   = tid & 63;
    const int w   = tid >> 6;
    const int lg  = l >> 4;          // lane group 0..3
    const int lr  = l & 15;          // lane row 0..15
    const int ms  = (w & 1) * 16;    // wave's M (query) strip
    const int np  = (w >> 1) * 2;    // wave's N granule pair base (0 or 2)

    const int b     = blockIdx.x & 7;   // batch == XCD round-robin slot
    const int qtile = blockIdx.x >> 3;
    const int qbase = qtile * QT;

    const int rr = tid >> 2;   // staging row (0..63)
    const int rq = tid & 3;    // staging quarter within row

    // ---------------- stage Q: load, normalize, bf16 -> LDS ----------------
    if (tid < QT * 4) {
        const float4* qp = reinterpret_cast<const float4*>(
            Qg + (size_t)(qbase + rr) * (BATCH * DIM) + b * DIM);
        float4 v[4];
        float ss = 0.f;
        #pragma unroll
        for (int c = 0; c < 4; ++c) {
            v[c] = qp[rq + 4 * c];
            ss += v[c].x * v[c].x + v[c].y * v[c].y + v[c].z * v[c].z + v[c].w * v[c].w;
        }
        ss += __shfl_xor(ss, 1);
        ss += __shfl_xor(ss, 2);
        const float sc = 1.f / (sqrtf(ss) + EPSV);
        #pragma unroll
        for (int c = 0; c < 4; ++c) {
            short4v s4 = { bf16b(v[c].x * sc), bf16b(v[c].y * sc),
                           bf16b(v[c].z * sc), bf16b(v[c].w * sc) };
            *reinterpret_cast<short4v*>(&Qsh[rr * QP + rq * 4 + 16 * c]) = s4;
        }
    }
    if (tid < QT) rsum[tid] = 0.f;
    __syncthreads();

    // Q A-fragments (persist in registers): rows ms+lr, k = kk*32 + lg*8 .. +7
    short8 aq[2];
    #pragma unroll
    for (int kk = 0; kk < 2; ++kk)
        aq[kk] = *reinterpret_cast<const short8*>(&Qsh[(ms + lr) * QP + kk * 32 + lg * 8]);

    // ========================= PASS A: row sums =========================
    float sums[4] = {0.f, 0.f, 0.f, 0.f};
    for (int t = 0; t < NT; ++t) {
        __syncthreads();
        {   // stage K tile (normalize -> bf16)
            const float4* kp = reinterpret_cast<const float4*>(
                Kg + (size_t)(t * KT + rr) * (BATCH * DIM) + b * DIM);
            float4 v[4];
            float ss = 0.f;
            #pragma unroll
            for (int c = 0; c < 4; ++c) {
                v[c] = kp[rq + 4 * c];
                ss += v[c].x * v[c].x + v[c].y * v[c].y + v[c].z * v[c].z + v[c].w * v[c].w;
            }
            ss += __shfl_xor(ss, 1);
            ss += __shfl_xor(ss, 2);
            const float sc = 1.f / (sqrtf(ss) + EPSV);
            #pragma unroll
            for (int c = 0; c < 4; ++c) {
                short4v s4 = { bf16b(v[c].x * sc), bf16b(v[c].y * sc),
                               bf16b(v[c].z * sc), bf16b(v[c].w * sc) };
                *reinterpret_cast<short4v*>(&Ksh[rr * QP + rq * 4 + 16 * c]) = s4;
            }
        }
        __syncthreads();
        #pragma unroll
        for (int g = 0; g < 2; ++g) {
            f32x4 acc = {0.f, 0.f, 0.f, 0.f};
            #pragma unroll
            for (int kk = 0; kk < 2; ++kk) {
                short8 bk = *reinterpret_cast<const short8*>(
                    &Ksh[((np + g) * 16 + lr) * QP + kk * 32 + lg * 8]);
                acc = __builtin_amdgcn_mfma_f32_16x16x32_bf16(aq[kk], bk, acc, 0, 0, 0);
            }
            #pragma unroll
            for (int r = 0; r < 4; ++r) {
                float c = acc[r];
                sums[r] += __expf(0.5f + 0.5f * c * c);
            }
        }
    }
    // reduce row sums over the 16 lanes of each group, combine across waves
    #pragma unroll
    for (int r = 0; r < 4; ++r) {
        float v = sums[r];
        v += __shfl_xor(v, 1);
        v += __shfl_xor(v, 2);
        v += __shfl_xor(v, 4);
        v += __shfl_xor(v, 8);
        sums[r] = v;
    }
    if (lr == 0) {
        #pragma unroll
        for (int r = 0; r < 4; ++r)
            atomicAdd(&rsum[ms + lg * 4 + r], sums[r]);
    }
    __syncthreads();
    float inv4[4];
    #pragma unroll
    for (int r = 0; r < 4; ++r)
        inv4[r] = 1.f / rsum[ms + lg * 4 + r];

    // ========================= PASS B: probs + PV =========================
    float* attn = out + (size_t)S_LEN * BATCH * DIM;
    f32x4 cacc[2];
    cacc[0] = (f32x4){0.f, 0.f, 0.f, 0.f};
    cacc[1] = (f32x4){0.f, 0.f, 0.f, 0.f};

    for (int t = 0; t < NT; ++t) {
        __syncthreads();   // previous tile's PV / attn-write done
        {   // stage K tile (normalize -> bf16)
            const float4* kp = reinterpret_cast<const float4*>(
                Kg + (size_t)(t * KT + rr) * (BATCH * DIM) + b * DIM);
            float4 v[4];
            float ss = 0.f;
            #pragma unroll
            for (int c = 0; c < 4; ++c) {
                v[c] = kp[rq + 4 * c];
                ss += v[c].x * v[c].x + v[c].y * v[c].y + v[c].z * v[c].z + v[c].w * v[c].w;
            }
            ss += __shfl_xor(ss, 1);
            ss += __shfl_xor(ss, 2);
            const float sc = 1.f / (sqrtf(ss) + EPSV);
            #pragma unroll
            for (int c = 0; c < 4; ++c) {
                short4v s4 = { bf16b(v[c].x * sc), bf16b(v[c].y * sc),
                               bf16b(v[c].z * sc), bf16b(v[c].w * sc) };
                *reinterpret_cast<short4v*>(&Ksh[rr * QP + rq * 4 + 16 * c]) = s4;
            }
        }
        {   // stage V tile transposed: VTs[d][k] bf16
            const float4* vp = reinterpret_cast<const float4*>(
                Vg + (size_t)(t * KT + rr) * (BATCH * DIM) + b * DIM);
            #pragma unroll
            for (int c = 0; c < 4; ++c) {
                float4 v = vp[rq + 4 * c];
                int d0 = rq * 4 + 16 * c;
                VTs[(d0 + 0) * QP + rr] = bf16b(v.x);
                VTs[(d0 + 1) * QP + rr] = bf16b(v.y);
                VTs[(d0 + 2) * QP + rr] = bf16b(v.z);
                VTs[(d0 + 3) * QP + rr] = bf16b(v.w);
            }
        }
        __syncthreads();
        // QK^T again -> probs -> Pf (fp32) + Pb (bf16)
        #pragma unroll
        for (int g = 0; g < 2; ++g) {
            f32x4 acc = {0.f, 0.f, 0.f, 0.f};
            #pragma unroll
            for (int kk = 0; kk < 2; ++kk) {
                short8 bk = *reinterpret_cast<const short8*>(
                    &Ksh[((np + g) * 16 + lr) * QP + kk * 32 + lg * 8]);
                acc = __builtin_amdgcn_mfma_f32_16x16x32_bf16(aq[kk], bk, acc, 0, 0, 0);
            }
            #pragma unroll
            for (int r = 0; r < 4; ++r) {
                float c = acc[r];
                float p = __expf(0.5f + 0.5f * c * c) * inv4[r];
                int q_r = ms + lg * 4 + r;
                int k_c = (np + g) * 16 + lr;
                Pf[q_r * PP + k_c] = p;
                Pb[q_r * QP + k_c] = bf16b(p);
            }
        }
        __syncthreads();
        // PV accumulate (MFMA) over this k-tile
        #pragma unroll
        for (int g = 0; g < 2; ++g) {
            #pragma unroll
            for (int kk = 0; kk < 2; ++kk) {
                short8 ap = *reinterpret_cast<const short8*>(
                    &Pb[(ms + lr) * QP + kk * 32 + lg * 8]);
                short8 bv = *reinterpret_cast<const short8*>(
                    &VTs[((np + g) * 16 + lr) * QP + kk * 32 + lg * 8]);
                cacc[g] = __builtin_amdgcn_mfma_f32_16x16x32_bf16(ap, bv, cacc[g], 0, 0, 0);
            }
        }
        // coalesced fp32 attn write from Pf (nontemporal: write-once stream,
        // keep K/V resident in L2). Use ext_vector f32x4 — the builtin
        // rejects HIP_vector_type.
        #pragma unroll
        for (int s = 0; s < 2; ++s) {
            int q  = s * 16 + (tid >> 4);
            int c4 = (tid & 15) * 4;
            f32x4 pv = *reinterpret_cast<const f32x4*>(&Pf[q * PP + c4]);
            __builtin_nontemporal_store(pv, reinterpret_cast<f32x4*>(
                attn + (size_t)(qbase + q) * (BATCH * S_LEN) + b * S_LEN + t * KT + c4));
        }
    }

    // ---------------- context write ----------------
    #pragma unroll
    for (int g = 0; g < 2; ++g) {
        #pragma unroll
        for (int r = 0; r < 4; ++r) {
            __builtin_nontemporal_store(cacc[g][r],
                out + (size_t)(qbase + ms + lg * 4 + r) * (BATCH * DIM)
                    + b * DIM + (np + g) * 16 + lr);
        }
    }
}

extern "C" void kernel_launch(void* const* d_in, const int* in_sizes, int n_in,
                              void* d_out, int out_size, void* d_ws, size_t ws_size,
                              hipStream_t stream)
{
    const float* q = (const float*)d_in[0];
    const float* k = (const float*)d_in[1];
    const float* v = (const float*)d_in[2];
    float* o = (float*)d_out;
    dim3 grid(BATCH * (S_LEN / QT));   // 512 blocks
    qattn<<<grid, 256, 0, stream>>>(q, k, v, o);
}

// Round 8
// 171.306 us; speedup vs baseline: 1.4237x; 1.4237x over previous
//
#include <hip/hip_runtime.h>

#define S_LEN 2048
#define BATCH 8
#define DIM   64
#define QT    16          // queries per block (fast path)
#define KT    64          // keys per k-tile
#define NT    32          // k-tiles (S/KT)
#define NQT   128         // 16-row tiles per batch (S/16)
#define PP    68          // fp32 P pitch (floats)
#define PBP   72          // bf16 P pitch (shorts)
#define EPSV  1e-8f

// ws layout (shorts): Q_pre [0, 1M), K_pre [1M, 2M), V_pre [2M, 3M)  => 6 MB
#define WS_K_OFF (1u << 20)
#define WS_V_OFF (1u << 21)
#define WS_NEED_BYTES (6u * 1024u * 1024u)

typedef __attribute__((ext_vector_type(8))) short short8;
typedef __attribute__((ext_vector_type(4))) short short4v;
typedef __attribute__((ext_vector_type(4))) float f32x4;

// round-to-nearest-even fp32 -> bf16 bits
__device__ __forceinline__ short bf16b(float x) {
    unsigned int u = __builtin_bit_cast(unsigned int, x);
    u = (u + 0x7fffu + ((u >> 16) & 1u)) >> 16;
    return (short)u;
}

// ---------------------------------------------------------------------------
// prep: normalize Q,K rows -> bf16 fragment-order; V -> bf16 transposed
// fragment-order. Fragment chunk layout (16B = 8 bf16 per chunk):
//   Q/K: chunk((b,tile16), kk, lg, row) at ((b*128+tile)*128 + kk*64+lg*16+row)
//        holds X_hat[tile*16+row][b][kk*32+lg*8 + j], j=0..7
//   V:   chunk(b,t,gd,kk,l) at (((b*32+t)*4+gd)*128 + kk*64 + l)
//        holds V[t*64+kk*32+(l>>4)*8+j][b][gd*16+(l&15)]
// ---------------------------------------------------------------------------
__global__ __launch_bounds__(256)
void prep(const float* __restrict__ Qg, const float* __restrict__ Kg,
          const float* __restrict__ Vg, short* __restrict__ ws)
{
    const int blk = blockIdx.x;
    const int tid = threadIdx.x;
    if (blk < 512) {
        const bool isK = blk >= 256;
        const float* src = isK ? Kg : Qg;
        short* dst = ws + (isK ? WS_K_OFF : 0u);
        const int rg = (blk & 255) * 64 + (tid >> 2);   // global row (s*8+b)
        const int rq = tid & 3;
        const int s = rg >> 3, b = rg & 7;
        const float4* rp = reinterpret_cast<const float4*>(src) + (size_t)rg * 16;
        float4 v[4];
        float ss = 0.f;
        #pragma unroll
        for (int c = 0; c < 4; ++c) {
            v[c] = rp[rq * 4 + c];                       // k = rq*16 + c*4 ..+3
            ss += v[c].x*v[c].x + v[c].y*v[c].y + v[c].z*v[c].z + v[c].w*v[c].w;
        }
        ss += __shfl_xor(ss, 1);
        ss += __shfl_xor(ss, 2);
        const float sc = 1.f / (sqrtf(ss) + EPSV);
        const float* pf = reinterpret_cast<const float*>(v);
        #pragma unroll
        for (int h = 0; h < 2; ++h) {
            const int c8 = rq * 2 + h;                   // 8-elem k-chunk id
            const int kk = c8 >> 2, lg = c8 & 3;         // k = kk*32+lg*8 == c8*8
            const int chunk = (b * NQT + (s >> 4)) * 128 + kk * 64 + lg * 16 + (s & 15);
            short8 o;
            #pragma unroll
            for (int j = 0; j < 8; ++j) o[j] = bf16b(pf[h * 8 + j] * sc);
            *reinterpret_cast<short8*>(dst + (size_t)chunk * 8) = o;
        }
    } else {
        const int cid = (blk - 512) * 256 + tid;         // 131072 chunks
        const int l  = cid & 63;
        const int kk = (cid >> 6) & 1;
        const int gd = (cid >> 7) & 3;
        const int t  = (cid >> 9) & 31;
        const int b  = cid >> 14;
        const int d  = gd * 16 + (l & 15);
        const int k0 = t * 64 + kk * 32 + (l >> 4) * 8;
        short8 o;
        #pragma unroll
        for (int j = 0; j < 8; ++j)
            o[j] = bf16b(Vg[((size_t)(k0 + j) * BATCH + b) * DIM + d]);
        *reinterpret_cast<short8*>(ws + WS_V_OFF + (size_t)cid * 8) = o;
    }
}

// ---------------------------------------------------------------------------
// Fast path: 1024 blocks (4/CU), 4 waves. Wave w owns k/d granule w.
// All MFMA operands loaded global->register (fragment-ordered, L2-resident).
// LDS only for the P cross-lane shuffle (~7 KB). Pass A: barrier-free.
// Pass B: 2 LDS-only raw barriers per tile (no vmcnt drain of the
// nontemporal attn store queue).
// ---------------------------------------------------------------------------
__global__ __launch_bounds__(256, 4)
void qattn2(const short* __restrict__ Qp, const short* __restrict__ Kp,
            const short* __restrict__ Vp, float* __restrict__ out)
{
    __shared__ float Pf[QT * PP];     // probs fp32 (coalesced attn write)
    __shared__ short Pb[QT * PBP];    // probs bf16 (PV A-operand)
    __shared__ float rsum[QT];

    const int tid = threadIdx.x;
    const int l   = tid & 63;
    const int w   = tid >> 6;        // wave = granule (k-cols in QK^T, d-cols in PV)
    const int lg  = l >> 4;
    const int lr  = l & 15;

    const int b     = blockIdx.x & 7;     // batch == XCD slot (K/V L2-resident)
    const int qt    = blockIdx.x >> 3;    // 0..127
    const int qbase = qt * QT;

    // Q A-fragments: rows lr, k = kk*32+lg*8 (all 4 waves read same -> L1 bcast)
    const short8* Qc = reinterpret_cast<const short8*>(Qp) + (size_t)(b * NQT + qt) * 128;
    const short8 aq0 = Qc[l];
    const short8 aq1 = Qc[64 + l];

    if (tid < QT) rsum[tid] = 0.f;
    __syncthreads();

    const short8* Kb = reinterpret_cast<const short8*>(Kp) + (size_t)b * NQT * 128;
    const short8* Vb = reinterpret_cast<const short8*>(Vp) + (size_t)b * NT * 4 * 128;

    // ===================== PASS A: row sums (no barriers) =====================
    float sums[4] = {0.f, 0.f, 0.f, 0.f};
    for (int t = 0; t < NT; ++t) {
        const short8* kc = Kb + (size_t)(4 * t + w) * 128 + l;
        const short8 k0 = kc[0];
        const short8 k1 = kc[64];
        f32x4 acc = {0.f, 0.f, 0.f, 0.f};
        acc = __builtin_amdgcn_mfma_f32_16x16x32_bf16(aq0, k0, acc, 0, 0, 0);
        acc = __builtin_amdgcn_mfma_f32_16x16x32_bf16(aq1, k1, acc, 0, 0, 0);
        #pragma unroll
        for (int r = 0; r < 4; ++r) {
            float c = acc[r];
            sums[r] += __expf(0.5f + 0.5f * c * c);
        }
    }
    #pragma unroll
    for (int r = 0; r < 4; ++r) {
        float v = sums[r];
        v += __shfl_xor(v, 1);
        v += __shfl_xor(v, 2);
        v += __shfl_xor(v, 4);
        v += __shfl_xor(v, 8);
        sums[r] = v;
    }
    if (lr == 0) {
        #pragma unroll
        for (int r = 0; r < 4; ++r)
            atomicAdd(&rsum[lg * 4 + r], sums[r]);
    }
    __syncthreads();
    float inv_[4];
    #pragma unroll
    for (int r = 0; r < 4; ++r) inv_[r] = 1.f / rsum[lg * 4 + r];

    // ===================== PASS B: probs + attn write + PV =====================
    float* attn = out + (size_t)S_LEN * BATCH * DIM;
    f32x4 cacc = {0.f, 0.f, 0.f, 0.f};

    // prefetch K frags for t=0
    short8 k0, k1;
    {
        const short8* kc = Kb + (size_t)w * 128 + l;
        k0 = kc[0]; k1 = kc[64];
    }

    for (int t = 0; t < NT; ++t) {
        // V frags for this tile + next K frags: issue loads early
        const short8* vc = Vb + (size_t)(t * 4 + w) * 128 + l;
        const short8 v0 = vc[0];
        const short8 v1 = vc[64];
        const int tn = (t + 1 < NT) ? t + 1 : t;
        const short8* kc = Kb + (size_t)(4 * tn + w) * 128 + l;
        const short8 kn0 = kc[0];
        const short8 kn1 = kc[64];

        // QK^T -> probs
        f32x4 acc = {0.f, 0.f, 0.f, 0.f};
        acc = __builtin_amdgcn_mfma_f32_16x16x32_bf16(aq0, k0, acc, 0, 0, 0);
        acc = __builtin_amdgcn_mfma_f32_16x16x32_bf16(aq1, k1, acc, 0, 0, 0);
        #pragma unroll
        for (int r = 0; r < 4; ++r) {
            float c = acc[r];
            float p = __expf(0.5f + 0.5f * c * c) * inv_[r];
            Pf[(lg * 4 + r) * PP + w * 16 + lr] = p;
            Pb[(lg * 4 + r) * PBP + w * 16 + lr] = bf16b(p);
        }
        // barrier 1: P writes visible to all waves (LDS-only wait)
        asm volatile("s_waitcnt lgkmcnt(0)" ::: "memory");
        __builtin_amdgcn_sched_barrier(0);
        __builtin_amdgcn_s_barrier();
        __builtin_amdgcn_sched_barrier(0);

        // PV accumulate (A = P rows lr, B = V^T granule w)
        const short8 ap0 = *reinterpret_cast<const short8*>(&Pb[lr * PBP + lg * 8]);
        const short8 ap1 = *reinterpret_cast<const short8*>(&Pb[lr * PBP + 32 + lg * 8]);
        cacc = __builtin_amdgcn_mfma_f32_16x16x32_bf16(ap0, v0, cacc, 0, 0, 0);
        cacc = __builtin_amdgcn_mfma_f32_16x16x32_bf16(ap1, v1, cacc, 0, 0, 0);

        // coalesced nontemporal attn write (16 rows x 64 cols fp32)
        {
            const int q  = tid >> 4;
            const int c4 = (tid & 15) * 4;
            f32x4 pv = *reinterpret_cast<const f32x4*>(&Pf[q * PP + c4]);
            __builtin_nontemporal_store(pv, reinterpret_cast<f32x4*>(
                attn + (size_t)(qbase + q) * (BATCH * S_LEN) + b * S_LEN + t * KT + c4));
        }
        // barrier 2: all waves done READING Pf/Pb before next tile overwrites
        asm volatile("s_waitcnt lgkmcnt(0)" ::: "memory");
        __builtin_amdgcn_sched_barrier(0);
        __builtin_amdgcn_s_barrier();
        __builtin_amdgcn_sched_barrier(0);

        k0 = kn0; k1 = kn1;
    }

    // context write: lane holds ctx[q=lg*4+r][d=w*16+lr]
    #pragma unroll
    for (int r = 0; r < 4; ++r) {
        out[(size_t)(qbase + lg * 4 + r) * (BATCH * DIM) + b * DIM + w * 16 + lr] = cacc[r];
    }
}

// ---------------------------------------------------------------------------
// Fallback (round-4 kernel, measured passing at 131 us): used when ws_size
// is too small for the prep buffers. Monolithic, no workspace.
// ---------------------------------------------------------------------------
#define FQT 32
#define FQP 72
#define FPP 68

__global__ __launch_bounds__(256, 4)
void qattn_fb(const float* __restrict__ Qg, const float* __restrict__ Kg,
              const float* __restrict__ Vg, float* __restrict__ out)
{
    __shared__ short Qsh[FQT * FQP];
    __shared__ short Ksh[KT * FQP];
    __shared__ short VTs[DIM * FQP];
    __shared__ short Pb [FQT * FQP];
    __shared__ float Pf [FQT * FPP];
    __shared__ float rsum[FQT];

    const int tid = threadIdx.x;
    const int l   = tid & 63;
    const int w   = tid >> 6;
    const int lg  = l >> 4;
    const int lr  = l & 15;
    const int ms  = (w & 1) * 16;
    const int np  = (w >> 1) * 2;

    const int b     = blockIdx.x & 7;
    const int qtile = blockIdx.x >> 3;
    const int qbase = qtile * FQT;

    const int rr = tid >> 2;
    const int rq = tid & 3;

    if (tid < FQT * 4) {
        const float4* qp = reinterpret_cast<const float4*>(
            Qg + (size_t)(qbase + rr) * (BATCH * DIM) + b * DIM);
        float4 v[4];
        float ss = 0.f;
        #pragma unroll
        for (int c = 0; c < 4; ++c) {
            v[c] = qp[rq + 4 * c];
            ss += v[c].x*v[c].x + v[c].y*v[c].y + v[c].z*v[c].z + v[c].w*v[c].w;
        }
        ss += __shfl_xor(ss, 1);
        ss += __shfl_xor(ss, 2);
        const float sc = 1.f / (sqrtf(ss) + EPSV);
        #pragma unroll
        for (int c = 0; c < 4; ++c) {
            short4v s4 = { bf16b(v[c].x * sc), bf16b(v[c].y * sc),
                           bf16b(v[c].z * sc), bf16b(v[c].w * sc) };
            *reinterpret_cast<short4v*>(&Qsh[rr * FQP + rq * 4 + 16 * c]) = s4;
        }
    }
    if (tid < FQT) rsum[tid] = 0.f;
    __syncthreads();

    short8 aq[2];
    #pragma unroll
    for (int kk = 0; kk < 2; ++kk)
        aq[kk] = *reinterpret_cast<const short8*>(&Qsh[(ms + lr) * FQP + kk * 32 + lg * 8]);

    float sums[4] = {0.f, 0.f, 0.f, 0.f};
    for (int t = 0; t < NT; ++t) {
        __syncthreads();
        {
            const float4* kp = reinterpret_cast<const float4*>(
                Kg + (size_t)(t * KT + rr) * (BATCH * DIM) + b * DIM);
            float4 v[4];
            float ss = 0.f;
            #pragma unroll
            for (int c = 0; c < 4; ++c) {
                v[c] = kp[rq + 4 * c];
                ss += v[c].x*v[c].x + v[c].y*v[c].y + v[c].z*v[c].z + v[c].w*v[c].w;
            }
            ss += __shfl_xor(ss, 1);
            ss += __shfl_xor(ss, 2);
            const float sc = 1.f / (sqrtf(ss) + EPSV);
            #pragma unroll
            for (int c = 0; c < 4; ++c) {
                short4v s4 = { bf16b(v[c].x * sc), bf16b(v[c].y * sc),
                               bf16b(v[c].z * sc), bf16b(v[c].w * sc) };
                *reinterpret_cast<short4v*>(&Ksh[rr * FQP + rq * 4 + 16 * c]) = s4;
            }
        }
        __syncthreads();
        #pragma unroll
        for (int g = 0; g < 2; ++g) {
            f32x4 acc = {0.f, 0.f, 0.f, 0.f};
            #pragma unroll
            for (int kk = 0; kk < 2; ++kk) {
                short8 bk = *reinterpret_cast<const short8*>(
                    &Ksh[((np + g) * 16 + lr) * FQP + kk * 32 + lg * 8]);
                acc = __builtin_amdgcn_mfma_f32_16x16x32_bf16(aq[kk], bk, acc, 0, 0, 0);
            }
            #pragma unroll
            for (int r = 0; r < 4; ++r) {
                float c = acc[r];
                sums[r] += __expf(0.5f + 0.5f * c * c);
            }
        }
    }
    #pragma unroll
    for (int r = 0; r < 4; ++r) {
        float v = sums[r];
        v += __shfl_xor(v, 1);
        v += __shfl_xor(v, 2);
        v += __shfl_xor(v, 4);
        v += __shfl_xor(v, 8);
        sums[r] = v;
    }
    if (lr == 0) {
        #pragma unroll
        for (int r = 0; r < 4; ++r)
            atomicAdd(&rsum[ms + lg * 4 + r], sums[r]);
    }
    __syncthreads();
    float inv4[4];
    #pragma unroll
    for (int r = 0; r < 4; ++r)
        inv4[r] = 1.f / rsum[ms + lg * 4 + r];

    float* attn = out + (size_t)S_LEN * BATCH * DIM;
    f32x4 cacc[2];
    cacc[0] = (f32x4){0.f, 0.f, 0.f, 0.f};
    cacc[1] = (f32x4){0.f, 0.f, 0.f, 0.f};

    for (int t = 0; t < NT; ++t) {
        __syncthreads();
        {
            const float4* kp = reinterpret_cast<const float4*>(
                Kg + (size_t)(t * KT + rr) * (BATCH * DIM) + b * DIM);
            float4 v[4];
            float ss = 0.f;
            #pragma unroll
            for (int c = 0; c < 4; ++c) {
                v[c] = kp[rq + 4 * c];
                ss += v[c].x*v[c].x + v[c].y*v[c].y + v[c].z*v[c].z + v[c].w*v[c].w;
            }
            ss += __shfl_xor(ss, 1);
            ss += __shfl_xor(ss, 2);
            const float sc = 1.f / (sqrtf(ss) + EPSV);
            #pragma unroll
            for (int c = 0; c < 4; ++c) {
                short4v s4 = { bf16b(v[c].x * sc), bf16b(v[c].y * sc),
                               bf16b(v[c].z * sc), bf16b(v[c].w * sc) };
                *reinterpret_cast<short4v*>(&Ksh[rr * FQP + rq * 4 + 16 * c]) = s4;
            }
        }
        {
            const float4* vp = reinterpret_cast<const float4*>(
                Vg + (size_t)(t * KT + rr) * (BATCH * DIM) + b * DIM);
            #pragma unroll
            for (int c = 0; c < 4; ++c) {
                float4 v = vp[rq + 4 * c];
                int d0 = rq * 4 + 16 * c;
                VTs[(d0 + 0) * FQP + rr] = bf16b(v.x);
                VTs[(d0 + 1) * FQP + rr] = bf16b(v.y);
                VTs[(d0 + 2) * FQP + rr] = bf16b(v.z);
                VTs[(d0 + 3) * FQP + rr] = bf16b(v.w);
            }
        }
        __syncthreads();
        #pragma unroll
        for (int g = 0; g < 2; ++g) {
            f32x4 acc = {0.f, 0.f, 0.f, 0.f};
            #pragma unroll
            for (int kk = 0; kk < 2; ++kk) {
                short8 bk = *reinterpret_cast<const short8*>(
                    &Ksh[((np + g) * 16 + lr) * FQP + kk * 32 + lg * 8]);
                acc = __builtin_amdgcn_mfma_f32_16x16x32_bf16(aq[kk], bk, acc, 0, 0, 0);
            }
            #pragma unroll
            for (int r = 0; r < 4; ++r) {
                float c = acc[r];
                float p = __expf(0.5f + 0.5f * c * c) * inv4[r];
                int q_r = ms + lg * 4 + r;
                int k_c = (np + g) * 16 + lr;
                Pf[q_r * FPP + k_c] = p;
                Pb[q_r * FQP + k_c] = bf16b(p);
            }
        }
        __syncthreads();
        #pragma unroll
        for (int g = 0; g < 2; ++g) {
            #pragma unroll
            for (int kk = 0; kk < 2; ++kk) {
                short8 ap = *reinterpret_cast<const short8*>(
                    &Pb[(ms + lr) * FQP + kk * 32 + lg * 8]);
                short8 bv = *reinterpret_cast<const short8*>(
                    &VTs[((np + g) * 16 + lr) * FQP + kk * 32 + lg * 8]);
                cacc[g] = __builtin_amdgcn_mfma_f32_16x16x32_bf16(ap, bv, cacc[g], 0, 0, 0);
            }
        }
        #pragma unroll
        for (int s = 0; s < 2; ++s) {
            int q  = s * 16 + (tid >> 4);
            int c4 = (tid & 15) * 4;
            f32x4 pv = *reinterpret_cast<const f32x4*>(&Pf[q * FPP + c4]);
            __builtin_nontemporal_store(pv, reinterpret_cast<f32x4*>(
                attn + (size_t)(qbase + q) * (BATCH * S_LEN) + b * S_LEN + t * KT + c4));
        }
    }

    #pragma unroll
    for (int g = 0; g < 2; ++g) {
        #pragma unroll
        for (int r = 0; r < 4; ++r) {
            __builtin_nontemporal_store(cacc[g][r],
                out + (size_t)(qbase + ms + lg * 4 + r) * (BATCH * DIM)
                    + b * DIM + (np + g) * 16 + lr);
        }
    }
}

extern "C" void kernel_launch(void* const* d_in, const int* in_sizes, int n_in,
                              void* d_out, int out_size, void* d_ws, size_t ws_size,
                              hipStream_t stream)
{
    const float* q = (const float*)d_in[0];
    const float* k = (const float*)d_in[1];
    const float* v = (const float*)d_in[2];
    float* o  = (float*)d_out;

    if (ws_size >= WS_NEED_BYTES && d_ws != nullptr) {
        short* ws = (short*)d_ws;
        prep<<<1024, 256, 0, stream>>>(q, k, v, ws);
        qattn2<<<1024, 256, 0, stream>>>(ws, ws + WS_K_OFF, ws + WS_V_OFF, o);
    } else {
        qattn_fb<<<BATCH * (S_LEN / FQT), 256, 0, stream>>>(q, k, v, o);
    }
}

// Round 11
// 169.578 us; speedup vs baseline: 1.4382x; 1.0102x over previous
//
#include <hip/hip_runtime.h>

#define S_LEN 2048
#define BATCH 8
#define DIM   64
#define QT    32          // queries per block (fast path)
#define KTILE 128         // keys per k-tile (8 granules x 16)
#define NT2   16          // k-tiles (S/KTILE)
#define NQT   128         // 16-row chunks per batch (S/16) in prep layout
#define PP    132         // fp32 P pitch (floats)
#define PBP   136         // bf16 P pitch (shorts)
#define EPSV  1e-8f

// ws layout (shorts): Q_pre [0, 1M), K_pre [1M, 2M), V_pre [2M, 3M)  => 6 MB
#define WS_K_OFF (1u << 20)
#define WS_V_OFF (1u << 21)
#define WS_NEED_BYTES (6u * 1024u * 1024u)

typedef __attribute__((ext_vector_type(8))) short short8;
typedef __attribute__((ext_vector_type(4))) short short4v;
typedef __attribute__((ext_vector_type(4))) float f32x4;

// round-to-nearest-even fp32 -> bf16 bits
__device__ __forceinline__ short bf16b(float x) {
    unsigned int u = __builtin_bit_cast(unsigned int, x);
    u = (u + 0x7fffu + ((u >> 16) & 1u)) >> 16;
    return (short)u;
}

#define LDS_BARRIER() do { \
    asm volatile("s_waitcnt lgkmcnt(0)" ::: "memory"); \
    __builtin_amdgcn_sched_barrier(0); \
    __builtin_amdgcn_s_barrier(); \
    __builtin_amdgcn_sched_barrier(0); \
} while (0)

// ---------------------------------------------------------------------------
// prep: normalize Q,K rows -> bf16 fragment-order; V -> bf16 transposed
// fragment-order. Fragment chunk layout (16B = 8 bf16 per chunk):
//   Q/K: chunk((b,tile16), kk, lg, row) at ((b*128+tile)*128 + kk*64+lg*16+row)
//        holds X_hat[tile*16+row][b][kk*32+lg*8 + j], j=0..7
//   V:   chunk(b,t,gd,kk,l) at (((b*32+t)*4+gd)*128 + kk*64 + l)
//        holds V[t*64+kk*32+(l>>4)*8+j][b][gd*16+(l&15)]
// ---------------------------------------------------------------------------
__global__ __launch_bounds__(256)
void prep(const float* __restrict__ Qg, const float* __restrict__ Kg,
          const float* __restrict__ Vg, short* __restrict__ ws)
{
    const int blk = blockIdx.x;
    const int tid = threadIdx.x;
    if (blk < 512) {
        const bool isK = blk >= 256;
        const float* src = isK ? Kg : Qg;
        short* dst = ws + (isK ? WS_K_OFF : 0u);
        const int rg = (blk & 255) * 64 + (tid >> 2);   // global row (s*8+b)
        const int rq = tid & 3;
        const int s = rg >> 3, b = rg & 7;
        const float4* rp = reinterpret_cast<const float4*>(src) + (size_t)rg * 16;
        float4 v[4];
        float ss = 0.f;
        #pragma unroll
        for (int c = 0; c < 4; ++c) {
            v[c] = rp[rq * 4 + c];                       // k = rq*16 + c*4 ..+3
            ss += v[c].x*v[c].x + v[c].y*v[c].y + v[c].z*v[c].z + v[c].w*v[c].w;
        }
        ss += __shfl_xor(ss, 1);
        ss += __shfl_xor(ss, 2);
        const float sc = 1.f / (sqrtf(ss) + EPSV);
        const float* pf = reinterpret_cast<const float*>(v);
        #pragma unroll
        for (int h = 0; h < 2; ++h) {
            const int c8 = rq * 2 + h;                   // 8-elem k-chunk id
            const int kk = c8 >> 2, lg = c8 & 3;         // k = kk*32+lg*8 == c8*8
            const int chunk = (b * NQT + (s >> 4)) * 128 + kk * 64 + lg * 16 + (s & 15);
            short8 o;
            #pragma unroll
            for (int j = 0; j < 8; ++j) o[j] = bf16b(pf[h * 8 + j] * sc);
            *reinterpret_cast<short8*>(dst + (size_t)chunk * 8) = o;
        }
    } else {
        const int cid = (blk - 512) * 256 + tid;         // 131072 chunks
        const int l  = cid & 63;
        const int kk = (cid >> 6) & 1;
        const int gd = (cid >> 7) & 3;
        const int t  = (cid >> 9) & 31;
        const int b  = cid >> 14;
        const int d  = gd * 16 + (l & 15);
        const int k0 = t * 64 + kk * 32 + (l >> 4) * 8;
        short8 o;
        #pragma unroll
        for (int j = 0; j < 8; ++j)
            o[j] = bf16b(Vg[((size_t)(k0 + j) * BATCH + b) * DIM + d]);
        *reinterpret_cast<short8*>(ws + WS_V_OFF + (size_t)cid * 8) = o;
    }
}

// ---------------------------------------------------------------------------
// Fast path v3: 512 blocks (2/CU), 8 waves (512 thr). QT=32 rows, KTILE=128.
// QK^T phase: wave w owns k-granule w (disjoint -> no duplicate K L2 reads).
// PV phase:   wave w = (mstrip=w>>2, dgran=w&3).
// K prefetched one tile ahead in registers; V issued early each tile.
// LDS only for the P cross-lane shuffle (~26 KB). Pass A barrier-free;
// pass B has 2 LDS-only barriers per tile (16 tiles vs 32 before).
// ---------------------------------------------------------------------------
__global__ __launch_bounds__(512, 4)
void qattn3(const short* __restrict__ Qp, const short* __restrict__ Kp,
            const short* __restrict__ Vp, float* __restrict__ out)
{
    __shared__ float Pf[QT * PP];     // probs fp32 (coalesced attn write)
    __shared__ short Pb[QT * PBP];    // probs bf16 (PV A-operand)
    __shared__ float rsum[QT];

    const int tid = threadIdx.x;
    const int l   = tid & 63;
    const int w   = tid >> 6;        // 0..7
    const int lg  = l >> 4;
    const int lr  = l & 15;
    const int kg  = w;               // QK phase: k-granule
    const int ms  = (w >> 2) * 16;   // PV phase: q-strip base
    const int dg  = w & 3;           // PV phase: d-granule

    const int b     = blockIdx.x & 7;     // batch == XCD slot (K/V L2-resident)
    const int qt    = blockIdx.x >> 3;    // 0..63
    const int qbase = qt * QT;

    // Q A-fragments for both 16-row strips
    const short8* Qp8 = reinterpret_cast<const short8*>(Qp);
    short8 aq[2][2];
    #pragma unroll
    for (int m = 0; m < 2; ++m) {
        const size_t base = (size_t)(b * NQT + qt * 2 + m) * 128;
        aq[m][0] = Qp8[base + l];
        aq[m][1] = Qp8[base + 64 + l];
    }

    if (tid < QT) rsum[tid] = 0.f;
    __syncthreads();

    const short8* Kb8 = reinterpret_cast<const short8*>(Kp) + (size_t)b * NQT * 128;
    const short8* Vb8 = reinterpret_cast<const short8*>(Vp) + (size_t)b * 32 * 4 * 128;

    // ===================== PASS A: row sums (no barriers) =====================
    float sums[2][4] = {{0.f,0.f,0.f,0.f},{0.f,0.f,0.f,0.f}};
    short8 k0 = Kb8[(size_t)kg * 128 + l];
    short8 k1 = Kb8[(size_t)kg * 128 + 64 + l];
    for (int t = 0; t < NT2; ++t) {
        const int tn = (t + 1 < NT2) ? t + 1 : t;
        const short8* kc = &Kb8[(size_t)(8 * tn + kg) * 128 + l];
        const short8 kn0 = kc[0];
        const short8 kn1 = kc[64];
        #pragma unroll
        for (int m = 0; m < 2; ++m) {
            f32x4 acc = {0.f, 0.f, 0.f, 0.f};
            acc = __builtin_amdgcn_mfma_f32_16x16x32_bf16(aq[m][0], k0, acc, 0, 0, 0);
            acc = __builtin_amdgcn_mfma_f32_16x16x32_bf16(aq[m][1], k1, acc, 0, 0, 0);
            #pragma unroll
            for (int r = 0; r < 4; ++r) {
                float c = acc[r];
                sums[m][r] += __expf(0.5f + 0.5f * c * c);
            }
        }
        k0 = kn0; k1 = kn1;
    }
    #pragma unroll
    for (int m = 0; m < 2; ++m)
    #pragma unroll
    for (int r = 0; r < 4; ++r) {
        float v = sums[m][r];
        v += __shfl_xor(v, 1);
        v += __shfl_xor(v, 2);
        v += __shfl_xor(v, 4);
        v += __shfl_xor(v, 8);
        sums[m][r] = v;
    }
    if (lr == 0) {
        #pragma unroll
        for (int m = 0; m < 2; ++m)
        #pragma unroll
        for (int r = 0; r < 4; ++r)
            atomicAdd(&rsum[m * 16 + lg * 4 + r], sums[m][r]);
    }
    __syncthreads();
    float inv_[2][4];
    #pragma unroll
    for (int m = 0; m < 2; ++m)
    #pragma unroll
    for (int r = 0; r < 4; ++r)
        inv_[m][r] = 1.f / rsum[m * 16 + lg * 4 + r];

    // ===================== PASS B: probs + attn write + PV =====================
    float* attn = out + (size_t)S_LEN * BATCH * DIM;
    f32x4 cacc = {0.f, 0.f, 0.f, 0.f};

    k0 = Kb8[(size_t)kg * 128 + l];
    k1 = Kb8[(size_t)kg * 128 + 64 + l];

    for (int t = 0; t < NT2; ++t) {
        // issue V frags (this tile) + next K frags early
        short8 bv[4];
        #pragma unroll
        for (int kk2 = 0; kk2 < 4; ++kk2) {
            const int tv = t * 2 + (kk2 >> 1);
            bv[kk2] = Vb8[(size_t)(tv * 4 + dg) * 128 + (kk2 & 1) * 64 + l];
        }
        const int tn = (t + 1 < NT2) ? t + 1 : t;
        const short8* kc = &Kb8[(size_t)(8 * tn + kg) * 128 + l];
        const short8 kn0 = kc[0];
        const short8 kn1 = kc[64];

        // QK^T -> probs for k-granule kg, both strips
        #pragma unroll
        for (int m = 0; m < 2; ++m) {
            f32x4 acc = {0.f, 0.f, 0.f, 0.f};
            acc = __builtin_amdgcn_mfma_f32_16x16x32_bf16(aq[m][0], k0, acc, 0, 0, 0);
            acc = __builtin_amdgcn_mfma_f32_16x16x32_bf16(aq[m][1], k1, acc, 0, 0, 0);
            #pragma unroll
            for (int r = 0; r < 4; ++r) {
                float c = acc[r];
                float p = __expf(0.5f + 0.5f * c * c) * inv_[m][r];
                const int q_r = m * 16 + lg * 4 + r;
                const int k_c = kg * 16 + lr;
                Pf[q_r * PP + k_c] = p;
                Pb[q_r * PBP + k_c] = bf16b(p);
            }
        }
        LDS_BARRIER();   // P visible to all waves

        // coalesced nontemporal attn write (32 rows x 128 cols fp32)
        {
            const int q = tid >> 4;
            const int c = (tid & 15) * 4;
            f32x4 pv0 = *reinterpret_cast<const f32x4*>(&Pf[q * PP + c]);
            f32x4 pv1 = *reinterpret_cast<const f32x4*>(&Pf[q * PP + 64 + c]);
            float* dst = attn + (size_t)(qbase + q) * (BATCH * S_LEN) + b * S_LEN + t * KTILE;
            __builtin_nontemporal_store(pv0, reinterpret_cast<f32x4*>(dst + c));
            __builtin_nontemporal_store(pv1, reinterpret_cast<f32x4*>(dst + 64 + c));
        }

        // PV accumulate: strip ms, d-granule dg, k = 0..127
        #pragma unroll
        for (int kk2 = 0; kk2 < 4; ++kk2) {
            const short8 ap = *reinterpret_cast<const short8*>(
                &Pb[(ms + lr) * PBP + kk2 * 32 + lg * 8]);
            cacc = __builtin_amdgcn_mfma_f32_16x16x32_bf16(ap, bv[kk2], cacc, 0, 0, 0);
        }
        LDS_BARRIER();   // all waves done reading Pf/Pb before overwrite

        k0 = kn0; k1 = kn1;
    }

    // context write: lane holds ctx[q=ms+lg*4+r][d=dg*16+lr]
    #pragma unroll
    for (int r = 0; r < 4; ++r) {
        out[(size_t)(qbase + ms + lg * 4 + r) * (BATCH * DIM) + b * DIM + dg * 16 + lr]
            = cacc[r];
    }
}

// ---------------------------------------------------------------------------
// Fallback (round-4 kernel, measured passing at 131 us kernel time): used
// when ws_size is too small for the prep buffers. Monolithic, no workspace.
// ---------------------------------------------------------------------------
#define FQT 32
#define FQP 72
#define FPP 68
#define FKT 64
#define FNT 32

__global__ __launch_bounds__(256, 4)
void qattn_fb(const float* __restrict__ Qg, const float* __restrict__ Kg,
              const float* __restrict__ Vg, float* __restrict__ out)
{
    __shared__ short Qsh[FQT * FQP];
    __shared__ short Ksh[FKT * FQP];
    __shared__ short VTs[DIM * FQP];
    __shared__ short Pb [FQT * FQP];
    __shared__ float Pf [FQT * FPP];
    __shared__ float rsum[FQT];

    const int tid = threadIdx.x;
    const int l   = tid & 63;
    const int w   = tid >> 6;
    const int lg  = l >> 4;
    const int lr  = l & 15;
    const int ms  = (w & 1) * 16;
    const int np  = (w >> 1) * 2;

    const int b     = blockIdx.x & 7;
    const int qtile = blockIdx.x >> 3;
    const int qbase = qtile * FQT;

    const int rr = tid >> 2;
    const int rq = tid & 3;

    if (tid < FQT * 4) {
        const float4* qp = reinterpret_cast<const float4*>(
            Qg + (size_t)(qbase + rr) * (BATCH * DIM) + b * DIM);
        float4 v[4];
        float ss = 0.f;
        #pragma unroll
        for (int c = 0; c < 4; ++c) {
            v[c] = qp[rq + 4 * c];
            ss += v[c].x*v[c].x + v[c].y*v[c].y + v[c].z*v[c].z + v[c].w*v[c].w;
        }
        ss += __shfl_xor(ss, 1);
        ss += __shfl_xor(ss, 2);
        const float sc = 1.f / (sqrtf(ss) + EPSV);
        #pragma unroll
        for (int c = 0; c < 4; ++c) {
            short4v s4 = { bf16b(v[c].x * sc), bf16b(v[c].y * sc),
                           bf16b(v[c].z * sc), bf16b(v[c].w * sc) };
            *reinterpret_cast<short4v*>(&Qsh[rr * FQP + rq * 4 + 16 * c]) = s4;
        }
    }
    if (tid < FQT) rsum[tid] = 0.f;
    __syncthreads();

    short8 aq[2];
    #pragma unroll
    for (int kk = 0; kk < 2; ++kk)
        aq[kk] = *reinterpret_cast<const short8*>(&Qsh[(ms + lr) * FQP + kk * 32 + lg * 8]);

    float sums[4] = {0.f, 0.f, 0.f, 0.f};
    for (int t = 0; t < FNT; ++t) {
        __syncthreads();
        {
            const float4* kp = reinterpret_cast<const float4*>(
                Kg + (size_t)(t * FKT + rr) * (BATCH * DIM) + b * DIM);
            float4 v[4];
            float ss = 0.f;
            #pragma unroll
            for (int c = 0; c < 4; ++c) {
                v[c] = kp[rq + 4 * c];
                ss += v[c].x*v[c].x + v[c].y*v[c].y + v[c].z*v[c].z + v[c].w*v[c].w;
            }
            ss += __shfl_xor(ss, 1);
            ss += __shfl_xor(ss, 2);
            const float sc = 1.f / (sqrtf(ss) + EPSV);
            #pragma unroll
            for (int c = 0; c < 4; ++c) {
                short4v s4 = { bf16b(v[c].x * sc), bf16b(v[c].y * sc),
                               bf16b(v[c].z * sc), bf16b(v[c].w * sc) };
                *reinterpret_cast<short4v*>(&Ksh[rr * FQP + rq * 4 + 16 * c]) = s4;
            }
        }
        __syncthreads();
        #pragma unroll
        for (int g = 0; g < 2; ++g) {
            f32x4 acc = {0.f, 0.f, 0.f, 0.f};
            #pragma unroll
            for (int kk = 0; kk < 2; ++kk) {
                short8 bk = *reinterpret_cast<const short8*>(
                    &Ksh[((np + g) * 16 + lr) * FQP + kk * 32 + lg * 8]);
                acc = __builtin_amdgcn_mfma_f32_16x16x32_bf16(aq[kk], bk, acc, 0, 0, 0);
            }
            #pragma unroll
            for (int r = 0; r < 4; ++r) {
                float c = acc[r];
                sums[r] += __expf(0.5f + 0.5f * c * c);
            }
        }
    }
    #pragma unroll
    for (int r = 0; r < 4; ++r) {
        float v = sums[r];
        v += __shfl_xor(v, 1);
        v += __shfl_xor(v, 2);
        v += __shfl_xor(v, 4);
        v += __shfl_xor(v, 8);
        sums[r] = v;
    }
    if (lr == 0) {
        #pragma unroll
        for (int r = 0; r < 4; ++r)
            atomicAdd(&rsum[ms + lg * 4 + r], sums[r]);
    }
    __syncthreads();
    float inv4[4];
    #pragma unroll
    for (int r = 0; r < 4; ++r)
        inv4[r] = 1.f / rsum[ms + lg * 4 + r];

    float* attn = out + (size_t)S_LEN * BATCH * DIM;
    f32x4 cacc[2];
    cacc[0] = (f32x4){0.f, 0.f, 0.f, 0.f};
    cacc[1] = (f32x4){0.f, 0.f, 0.f, 0.f};

    for (int t = 0; t < FNT; ++t) {
        __syncthreads();
        {
            const float4* kp = reinterpret_cast<const float4*>(
                Kg + (size_t)(t * FKT + rr) * (BATCH * DIM) + b * DIM);
            float4 v[4];
            float ss = 0.f;
            #pragma unroll
            for (int c = 0; c < 4; ++c) {
                v[c] = kp[rq + 4 * c];
                ss += v[c].x*v[c].x + v[c].y*v[c].y + v[c].z*v[c].z + v[c].w*v[c].w;
            }
            ss += __shfl_xor(ss, 1);
            ss += __shfl_xor(ss, 2);
            const float sc = 1.f / (sqrtf(ss) + EPSV);
            #pragma unroll
            for (int c = 0; c < 4; ++c) {
                short4v s4 = { bf16b(v[c].x * sc), bf16b(v[c].y * sc),
                               bf16b(v[c].z * sc), bf16b(v[c].w * sc) };
                *reinterpret_cast<short4v*>(&Ksh[rr * FQP + rq * 4 + 16 * c]) = s4;
            }
        }
        {
            const float4* vp = reinterpret_cast<const float4*>(
                Vg + (size_t)(t * FKT + rr) * (BATCH * DIM) + b * DIM);
            #pragma unroll
            for (int c = 0; c < 4; ++c) {
                float4 v = vp[rq + 4 * c];
                int d0 = rq * 4 + 16 * c;
                VTs[(d0 + 0) * FQP + rr] = bf16b(v.x);
                VTs[(d0 + 1) * FQP + rr] = bf16b(v.y);
                VTs[(d0 + 2) * FQP + rr] = bf16b(v.z);
                VTs[(d0 + 3) * FQP + rr] = bf16b(v.w);
            }
        }
        __syncthreads();
        #pragma unroll
        for (int g = 0; g < 2; ++g) {
            f32x4 acc = {0.f, 0.f, 0.f, 0.f};
            #pragma unroll
            for (int kk = 0; kk < 2; ++kk) {
                short8 bk = *reinterpret_cast<const short8*>(
                    &Ksh[((np + g) * 16 + lr) * FQP + kk * 32 + lg * 8]);
                acc = __builtin_amdgcn_mfma_f32_16x16x32_bf16(aq[kk], bk, acc, 0, 0, 0);
            }
            #pragma unroll
            for (int r = 0; r < 4; ++r) {
                float c = acc[r];
                float p = __expf(0.5f + 0.5f * c * c) * inv4[r];
                int q_r = ms + lg * 4 + r;
                int k_c = (np + g) * 16 + lr;
                Pf[q_r * FPP + k_c] = p;
                Pb[q_r * FQP + k_c] = bf16b(p);
            }
        }
        __syncthreads();
        #pragma unroll
        for (int g = 0; g < 2; ++g) {
            #pragma unroll
            for (int kk = 0; kk < 2; ++kk) {
                short8 ap = *reinterpret_cast<const short8*>(
                    &Pb[(ms + lr) * FQP + kk * 32 + lg * 8]);
                short8 bv = *reinterpret_cast<const short8*>(
                    &VTs[((np + g) * 16 + lr) * FQP + kk * 32 + lg * 8]);
                cacc[g] = __builtin_amdgcn_mfma_f32_16x16x32_bf16(ap, bv, cacc[g], 0, 0, 0);
            }
        }
        #pragma unroll
        for (int s = 0; s < 2; ++s) {
            int q  = s * 16 + (tid >> 4);
            int c4 = (tid & 15) * 4;
            f32x4 pv = *reinterpret_cast<const f32x4*>(&Pf[q * FPP + c4]);
            __builtin_nontemporal_store(pv, reinterpret_cast<f32x4*>(
                attn + (size_t)(qbase + q) * (BATCH * S_LEN) + b * S_LEN + t * FKT + c4));
        }
    }

    #pragma unroll
    for (int g = 0; g < 2; ++g) {
        #pragma unroll
        for (int r = 0; r < 4; ++r) {
            __builtin_nontemporal_store(cacc[g][r],
                out + (size_t)(qbase + ms + lg * 4 + r) * (BATCH * DIM)
                    + b * DIM + (np + g) * 16 + lr);
        }
    }
}

extern "C" void kernel_launch(void* const* d_in, const int* in_sizes, int n_in,
                              void* d_out, int out_size, void* d_ws, size_t ws_size,
                              hipStream_t stream)
{
    const float* q = (const float*)d_in[0];
    const float* k = (const float*)d_in[1];
    const float* v = (const float*)d_in[2];
    float* o  = (float*)d_out;

    if (ws_size >= WS_NEED_BYTES && d_ws != nullptr) {
        short* ws = (short*)d_ws;
        prep<<<1024, 256, 0, stream>>>(q, k, v, ws);
        qattn3<<<BATCH * (S_LEN / QT), 512, 0, stream>>>(ws, ws + WS_K_OFF, ws + WS_V_OFF, o);
    } else {
        qattn_fb<<<BATCH * (S_LEN / FQT), 256, 0, stream>>>(q, k, v, o);
    }
}